// Round 8
// baseline (15969.029 us; speedup 1.0000x reference)
//
#include <hip/hip_runtime.h>

typedef unsigned short u16;
typedef unsigned int u32;
typedef __attribute__((ext_vector_type(8))) short bf16x8;
typedef __attribute__((ext_vector_type(4))) float f32x4;
typedef __attribute__((ext_vector_type(4))) unsigned int u32x4;

#define B_ 512
#define T_ 1024
#define F_ 128
#define H_ 512
#define G_ 2048
#define LH_ 1024

#define MFMA16(a,b,c) (c) = __builtin_amdgcn_mfma_f32_16x16x32_bf16((a),(b),(c),0,0,0)

__device__ __forceinline__ u16 f2bf(float f) {
  unsigned u = __float_as_uint(f);
  unsigned r = (u + 0x7fffu + ((u >> 16) & 1u)) >> 16;
  return (u16)r;
}
__device__ __forceinline__ float bf2f(u16 h) {
  return __uint_as_float(((unsigned)h) << 16);
}

// ---------------- workspace layout (bytes) ----------------
constexpr size_t O_HPK     = 0;                               // u32 packed h, 2 bufs: 2 MB
constexpr size_t O_FL      = O_HPK + (size_t)2 * B_ * H_ * 4; // per-producer step flags
constexpr size_t O_MSET    = O_FL + 4096;                     // memset [0, O_MSET)
constexpr size_t O_WHH_HI  = O_MSET;
constexpr size_t O_WHH_LO  = O_WHH_HI + (size_t)G_ * H_ * 2;
constexpr size_t O_WIH_HI  = O_WHH_LO + (size_t)G_ * H_ * 2;
constexpr size_t O_WIH_LO  = O_WIH_HI + (size_t)G_ * F_ * 2;
constexpr size_t O_BIAS    = O_WIH_LO + (size_t)G_ * F_ * 2;
constexpr size_t O_HT      = O_BIAS + (size_t)G_ * 4;
constexpr size_t O_Z       = O_HT + (size_t)B_ * H_ * 4;

// ---------------- LDS layout ----------------
constexpr unsigned SM_WHH_LO = 65536;    // sWhhHi [64][512] u16 swizzled at 0
constexpr unsigned SM_XC     = 131072;   // partial-acc exchange [4 rt][16 j][64 l] f32 = 16 KB
constexpr unsigned SM_BIAS   = 147456;   // f32[64]
constexpr unsigned SM_READY  = 147712;   // u32[32]
constexpr unsigned SMEM_BYTES = 147840;

// ---------------- weight prep: permute + split to hi/lo bf16 ----------------
// permuted gate-col P = 64*nb + 16*g + u'  (unit u = 16*nb + u', g in {i,f,g,o})
__global__ void prep_weights(const float* __restrict__ Wih, const float* __restrict__ Whh,
                             const float* __restrict__ bih, const float* __restrict__ bhh,
                             u16* __restrict__ WhhHi, u16* __restrict__ WhhLo,
                             u16* __restrict__ WihHi, u16* __restrict__ WihLo,
                             float* __restrict__ bias) {
  int P = blockIdx.x;
  int nb = P >> 6, g = (P >> 4) & 3, u = P & 15;
  int orig = g * H_ + (nb << 4) + u;
  for (int k = threadIdx.x; k < H_; k += 128) {
    float w = Whh[(size_t)orig * H_ + k];
    u16 hi = f2bf(w);
    WhhHi[(size_t)P * H_ + k] = hi;
    WhhLo[(size_t)P * H_ + k] = f2bf(w - bf2f(hi));
  }
  {
    int k = threadIdx.x;
    float w = Wih[(size_t)orig * F_ + k];
    u16 hi = f2bf(w);
    WihHi[(size_t)P * F_ + k] = hi;
    WihLo[(size_t)P * F_ + k] = f2bf(w - bf2f(hi));
  }
  if (threadIdx.x == 0) bias[P] = bih[orig] + bhh[orig];
}

// ---------------- helpers ----------------
__device__ __forceinline__ u32x4 ald16(const u32* p) {   // system-coherent 16B load
  u32x4 r;
  asm volatile("global_load_dwordx4 %0, %1, off sc0 sc1" : "=&v"(r) : "v"(p));
  return r;
}
__device__ __forceinline__ u32x4 pld16(const float* p) { // plain cacheable 16B load
  u32x4 r;
  asm volatile("global_load_dwordx4 %0, %1, off" : "=&v"(r) : "v"(p));
  return r;
}

__device__ __forceinline__ void unpack(u32x4 a, u32x4 b, bf16x8& hi, bf16x8& lo) {
  #pragma unroll
  for (int j = 0; j < 4; ++j) { hi[j] = (short)(a[j] & 0xffffu); lo[j] = (short)(a[j] >> 16); }
  #pragma unroll
  for (int j = 0; j < 4; ++j) { hi[4 + j] = (short)(b[j] & 0xffffu); lo[4 + j] = (short)(b[j] >> 16); }
}

__device__ __forceinline__ void cvt8(u32x4 a, u32x4 b, bf16x8& hi, bf16x8& lo) {
  #pragma unroll
  for (int j = 0; j < 8; ++j) {
    float f = __uint_as_float(j < 4 ? a[j] : b[j - 4]);
    u16 h = f2bf(f);
    hi[j] = (short)h;
    lo[j] = (short)f2bf(f - bf2f(h));
  }
}

__device__ __forceinline__ bf16x8 ldB(const u16* base, int r, int k8) {
  return *(const bf16x8*)(base + r * 512 + ((k8 ^ (r & 7)) << 3));
}

// LDS gate: spin (lgkmcnt only!) until both producers of a chunk reached step t
__device__ __forceinline__ void gate2(u32* sReady, int p0, u32 t) {
  long fuse = 200000000;
  for (;;) {
    u32 a = __hip_atomic_load(&sReady[p0],     __ATOMIC_RELAXED, __HIP_MEMORY_SCOPE_WORKGROUP);
    u32 b = __hip_atomic_load(&sReady[p0 + 1], __ATOMIC_RELAXED, __HIP_MEMORY_SCOPE_WORKGROUP);
    if (a >= t && b >= t) break;
    __builtin_amdgcn_s_sleep(1);
    if (--fuse == 0) break;
  }
}

// ---------------- persistent LSTM kernel ----------------
// grid 256 = 8 row-groups (m = bid&7) x 32 unit-blocks (nb = bid>>3)
// 576 threads = 8 compute waves (4 row-tiles x 2 K-halves) + 1 relay wave
__global__ __launch_bounds__(576, 1) void lstm_persistent(
    const float* __restrict__ x,
    const u16* __restrict__ WhhHi, const u16* __restrict__ WhhLo,
    const u16* __restrict__ WihHi, const u16* __restrict__ WihLo,
    const float* __restrict__ bias,
    u32* __restrict__ hPk, u32* __restrict__ fl, float* __restrict__ hT) {
  extern __shared__ char smem[];
  u16* sWhhHi  = (u16*)(smem);
  u16* sWhhLo  = (u16*)(smem + SM_WHH_LO);
  float* sXc   = (float*)(smem + SM_XC);
  float* sBias = (float*)(smem + SM_BIAS);
  u32* sReady  = (u32*)(smem + SM_READY);

  const int tid = threadIdx.x;
  const int w = tid >> 6, l = tid & 63;
  const int m  = blockIdx.x & 7;
  const int nb = blockIdx.x >> 3;
  const int Pbase = 64 * nb;
  const int l15 = l & 15, l4 = l >> 4;
  const bool comp = (w < 8);
  const int rt = comp ? (w >> 1) : 0;
  const int cp = comp ? (w & 1) : 0;

  // ---- one-time: resident Whh slice (swizzled), bias, ready flags ----
  for (int i = tid; i < 4096; i += 576) {
    int r = i >> 6, k8 = i & 63;
    unsigned dst = r * 512 + ((k8 ^ (r & 7)) << 3);
    *(bf16x8*)(sWhhHi + dst) = *(const bf16x8*)(WhhHi + (size_t)(Pbase + r) * H_ + k8 * 8);
    *(bf16x8*)(sWhhLo + dst) = *(const bf16x8*)(WhhLo + (size_t)(Pbase + r) * H_ + k8 * 8);
  }
  if (tid < 64) sBias[tid] = bias[Pbase + tid];
  if (tid < 32) sReady[tid] = 0;

  // ---- one-time: Wih fragments into registers (4 col-tiles x 2 k-chunks of this K-half) ----
  bf16x8 wfh[4][2], wfl[4][2];
  if (comp) {
    #pragma unroll
    for (int ct = 0; ct < 4; ++ct)
      #pragma unroll
      for (int ch = 0; ch < 2; ++ch) {
        int gcol = 16 * ct + l15;
        int k8i = 8 * cp + 4 * ch + l4;
        wfh[ct][ch] = *(const bf16x8*)(WihHi + (size_t)(Pbase + gcol) * F_ + k8i * 8);
        wfl[ct][ch] = *(const bf16x8*)(WihLo + (size_t)(Pbase + gcol) * F_ + k8i * 8);
      }
  }
  __syncthreads();

  float bi = 0.f, bf_ = 0.f, bg = 0.f, bo = 0.f;
  if (comp) { bi = sBias[l15]; bf_ = sBias[16 + l15]; bg = sBias[32 + l15]; bo = sBias[48 + l15]; }

  const int arow = 64 * m + 16 * rt + l15;

  // prologue: x(0) prefetch (this wave's K-half of F), drained before loop
  u32x4 xa[2], xb[2];
  if (comp) {
    const float* xr = x + (size_t)arow * T_ * F_ + 64 * cp + 8 * l4;
    xa[0] = pld16(xr);      xb[0] = pld16(xr + 4);
    xa[1] = pld16(xr + 32); xb[1] = pld16(xr + 36);
  }
  asm volatile("s_waitcnt vmcnt(0)" ::: "memory");

  float cr[4] = {0.f, 0.f, 0.f, 0.f};   // cell state, cp0 only, static q-index

  #pragma unroll 1
  for (int t = 0; t < T_; ++t) {
    const u32* hcur = hPk + (size_t)(t & 1) * B_ * H_;
    u32* hnxt = hPk + (size_t)((t & 1) ^ 1) * B_ * H_;

    f32x4 acc0 = {0.f,0.f,0.f,0.f}, acc1 = {0.f,0.f,0.f,0.f};
    f32x4 acc2 = {0.f,0.f,0.f,0.f}, acc3 = {0.f,0.f,0.f,0.f};

    if (comp) {
      const u32* hrowt = hcur + (size_t)arow * H_ + 256 * cp + 8 * l4;
      u32x4 Aa[4], Ab[4];
      // gated issue of chunks 0..2 (LDS gates; vmcnt untouched by polling)
      if (t > 0) {
        gate2(sReady, 16 * cp + 0, (u32)t); Aa[0] = ald16(hrowt);      Ab[0] = ald16(hrowt + 4);
        gate2(sReady, 16 * cp + 2, (u32)t); Aa[1] = ald16(hrowt + 32); Ab[1] = ald16(hrowt + 36);
        gate2(sReady, 16 * cp + 4, (u32)t); Aa[2] = ald16(hrowt + 64); Ab[2] = ald16(hrowt + 68);
      }

      // ---- x-part (this K-half of F), overlaps h-load flight ----
      #pragma unroll
      for (int ch = 0; ch < 2; ++ch) {
        bf16x8 xh, xl;
        cvt8(xa[ch], xb[ch], xh, xl);
        MFMA16(xh, wfh[0][ch], acc0); MFMA16(xl, wfh[0][ch], acc0); MFMA16(xh, wfl[0][ch], acc0);
        MFMA16(xh, wfh[1][ch], acc1); MFMA16(xl, wfh[1][ch], acc1); MFMA16(xh, wfl[1][ch], acc1);
        MFMA16(xh, wfh[2][ch], acc2); MFMA16(xl, wfh[2][ch], acc2); MFMA16(xh, wfl[2][ch], acc2);
        MFMA16(xh, wfh[3][ch], acc3); MFMA16(xl, wfh[3][ch], acc3); MFMA16(xh, wfl[3][ch], acc3);
      }

      // ---- h-part: 8 K=32 chunks over this K-half, all 64 cols, counted vmcnt ----
      if (t > 0) {
        #pragma unroll
        for (int ch = 0; ch < 8; ++ch) {
          if (ch < 5) {
            gate2(sReady, 16 * cp + 2 * (ch + 3), (u32)t);
            Aa[(ch + 3) & 3] = ald16(hrowt + 32 * (ch + 3));
            Ab[(ch + 3) & 3] = ald16(hrowt + 32 * (ch + 3) + 4);
          }
          if (ch < 5)       asm volatile("s_waitcnt vmcnt(6)");
          else if (ch == 5) asm volatile("s_waitcnt vmcnt(4)");
          else if (ch == 6) asm volatile("s_waitcnt vmcnt(2)");
          else              asm volatile("s_waitcnt vmcnt(0)");
          __builtin_amdgcn_sched_barrier(0);
          bf16x8 ah, al;
          unpack(Aa[ch & 3], Ab[ch & 3], ah, al);
          int k8 = 32 * cp + 4 * ch + l4;
          bf16x8 bh, bl;
          bh = ldB(sWhhHi, l15, k8);      bl = ldB(sWhhLo, l15, k8);
          MFMA16(ah, bh, acc0); MFMA16(al, bh, acc0); MFMA16(ah, bl, acc0);
          bh = ldB(sWhhHi, 16 + l15, k8); bl = ldB(sWhhLo, 16 + l15, k8);
          MFMA16(ah, bh, acc1); MFMA16(al, bh, acc1); MFMA16(ah, bl, acc1);
          bh = ldB(sWhhHi, 32 + l15, k8); bl = ldB(sWhhLo, 32 + l15, k8);
          MFMA16(ah, bh, acc2); MFMA16(al, bh, acc2); MFMA16(ah, bl, acc2);
          bh = ldB(sWhhHi, 48 + l15, k8); bl = ldB(sWhhLo, 48 + l15, k8);
          MFMA16(ah, bh, acc3); MFMA16(al, bh, acc3); MFMA16(ah, bl, acc3);
        }
      }

      // ---- cp1: publish K-high partials (transposed conflict-free layout) ----
      if (cp == 1) {
        float* bse = sXc + (rt * 16) * 64 + l;
        bse[0 * 64]  = acc0[0]; bse[1 * 64]  = acc0[1]; bse[2 * 64]  = acc0[2]; bse[3 * 64]  = acc0[3];
        bse[4 * 64]  = acc1[0]; bse[5 * 64]  = acc1[1]; bse[6 * 64]  = acc1[2]; bse[7 * 64]  = acc1[3];
        bse[8 * 64]  = acc2[0]; bse[9 * 64]  = acc2[1]; bse[10 * 64] = acc2[2]; bse[11 * 64] = acc2[3];
        bse[12 * 64] = acc3[0]; bse[13 * 64] = acc3[1]; bse[14 * 64] = acc3[2]; bse[15 * 64] = acc3[3];
      }
    } else if (t > 0) {
      // ---- relay wave: forward global flags into LDS as they land ----
      if (l < 32) {
        const u32* fp = fl + m * 32 + l;
        long fuse = 400000000;
        u32 v = __hip_atomic_load(fp, __ATOMIC_RELAXED, __HIP_MEMORY_SCOPE_SYSTEM);
        while (v < (u32)t) {
          __builtin_amdgcn_s_sleep(2);
          v = __hip_atomic_load(fp, __ATOMIC_RELAXED, __HIP_MEMORY_SCOPE_SYSTEM);
          if (--fuse == 0) break;
        }
        __hip_atomic_store(&sReady[l], v, __ATOMIC_RELAXED, __HIP_MEMORY_SCOPE_WORKGROUP);
      }
    }

    __syncthreads();   // A: partials published; sReady stable for stragglers

    // ---- x(t+1) prefetch (issued before elementwise; drained at step end) ----
    if (comp) {
      int tp = (t + 1 < T_) ? t + 1 : 0;
      const float* xr = x + (size_t)arow * T_ * F_ + (size_t)tp * F_ + 64 * cp + 8 * l4;
      xa[0] = pld16(xr);      xb[0] = pld16(xr + 4);
      xa[1] = pld16(xr + 32); xb[1] = pld16(xr + 36);
    }

    // ---- cp0: fold partials, elementwise LSTM update (c in VGPRs), packed h store ----
    if (comp && cp == 0) {
      const float* bse = sXc + (rt * 16) * 64 + l;
      float p[16];
      #pragma unroll
      for (int j = 0; j < 16; ++j) p[j] = bse[j * 64];
      #pragma unroll
      for (int q = 0; q < 4; ++q) {
        float gi = acc0[q] + p[q]      + bi;
        float gf = acc1[q] + p[4 + q]  + bf_;
        float gg = acc2[q] + p[8 + q]  + bg;
        float go = acc3[q] + p[12 + q] + bo;
        float ii = 1.f / (1.f + __expf(-gi));
        float ff = 1.f / (1.f + __expf(-gf));
        float gG = 1.f - 2.f / (__expf(2.f * gg) + 1.f);
        float oo = 1.f / (1.f + __expf(-go));
        float c = ff * cr[q] + ii * gG;
        cr[q] = c;
        float h = oo * (1.f - 2.f / (__expf(2.f * c) + 1.f));
        u16 hb = f2bf(h);
        u16 lb = f2bf(h - bf2f(hb));
        u32 pk = (u32)hb | ((u32)lb << 16);
        size_t idx = (size_t)(64 * m + 16 * rt + 4 * l4 + q) * H_ + 16 * nb + l15;
        __hip_atomic_store(&hnxt[idx], pk, __ATOMIC_RELAXED, __HIP_MEMORY_SCOPE_SYSTEM);
        if (t == T_ - 1) hT[idx] = h;
      }
    }

    // ---- drain (per wave), barrier, single flag store, then isolate it from vmcnt ----
    asm volatile("s_waitcnt vmcnt(0)" ::: "memory");
    __syncthreads();   // B
    if (tid == 0) {
      __hip_atomic_store(&fl[m * 32 + nb], (u32)(t + 1), __ATOMIC_RELAXED, __HIP_MEMORY_SCOPE_SYSTEM);
      asm volatile("s_waitcnt vmcnt(0)" ::: "memory");
    }
  }
}

// ---------------- head: z = relu(hT @ W1^T + b1) ----------------
__global__ __launch_bounds__(256) void head1(const float* __restrict__ hT,
                                             const float* __restrict__ W1,
                                             const float* __restrict__ b1,
                                             float* __restrict__ z) {
  __shared__ float sA[64][16];
  __shared__ float sBt[16][64];
  int tx = threadIdx.x & 15, ty = threadIdx.x >> 4;
  int row0 = blockIdx.y * 64, col0 = blockIdx.x * 64;
  float acc[4][4] = {};
  for (int k0 = 0; k0 < H_; k0 += 16) {
    int c = threadIdx.x >> 2, kk4 = (threadIdx.x & 3) * 4;
    float4 av = *(const float4*)(hT + (size_t)(row0 + c) * H_ + k0 + kk4);
    *(float4*)&sA[c][kk4] = av;
    float4 bv = *(const float4*)(W1 + (size_t)(col0 + c) * H_ + k0 + kk4);
    sBt[kk4 + 0][c] = bv.x; sBt[kk4 + 1][c] = bv.y;
    sBt[kk4 + 2][c] = bv.z; sBt[kk4 + 3][c] = bv.w;
    __syncthreads();
    #pragma unroll
    for (int kk = 0; kk < 16; ++kk) {
      float a0 = sA[ty * 4 + 0][kk], a1 = sA[ty * 4 + 1][kk];
      float a2 = sA[ty * 4 + 2][kk], a3 = sA[ty * 4 + 3][kk];
      float b0 = sBt[kk][tx * 4 + 0], b1v = sBt[kk][tx * 4 + 1];
      float b2v = sBt[kk][tx * 4 + 2], b3 = sBt[kk][tx * 4 + 3];
      acc[0][0] += a0 * b0; acc[0][1] += a0 * b1v; acc[0][2] += a0 * b2v; acc[0][3] += a0 * b3;
      acc[1][0] += a1 * b0; acc[1][1] += a1 * b1v; acc[1][2] += a1 * b2v; acc[1][3] += a1 * b3;
      acc[2][0] += a2 * b0; acc[2][1] += a2 * b1v; acc[2][2] += a2 * b2v; acc[2][3] += a2 * b3;
      acc[3][0] += a3 * b0; acc[3][1] += a3 * b1v; acc[3][2] += a3 * b2v; acc[3][3] += a3 * b3;
    }
    __syncthreads();
  }
  #pragma unroll
  for (int i = 0; i < 4; ++i)
    #pragma unroll
    for (int j = 0; j < 4; ++j) {
      int rr = row0 + ty * 4 + i, cc = col0 + tx * 4 + j;
      float v = acc[i][j] + b1[cc];
      z[(size_t)rr * LH_ + cc] = v > 0.f ? v : 0.f;
    }
}

// ---------------- head: out[b] = z[b,:] . W2 + b2 ----------------
__global__ __launch_bounds__(256) void head2(const float* __restrict__ z,
                                             const float* __restrict__ W2,
                                             const float* __restrict__ b2,
                                             float* __restrict__ out) {
  int b = blockIdx.x;
  float p = 0.f;
  for (int j = threadIdx.x; j < LH_; j += 256) p += z[(size_t)b * LH_ + j] * W2[j];
  #pragma unroll
  for (int off = 32; off > 0; off >>= 1) p += __shfl_down(p, off);
  __shared__ float red[4];
  if ((threadIdx.x & 63) == 0) red[threadIdx.x >> 6] = p;
  __syncthreads();
  if (threadIdx.x == 0) out[b] = red[0] + red[1] + red[2] + red[3] + b2[0];
}

// ---------------- launch ----------------
extern "C" void kernel_launch(void* const* d_in, const int* in_sizes, int n_in,
                              void* d_out, int out_size, void* d_ws, size_t ws_size,
                              hipStream_t stream) {
  const float* x    = (const float*)d_in[0];
  const float* Wih  = (const float*)d_in[1];
  const float* Whh  = (const float*)d_in[2];
  const float* bih  = (const float*)d_in[3];
  const float* bhh  = (const float*)d_in[4];
  const float* W1   = (const float*)d_in[5];
  const float* b1   = (const float*)d_in[6];
  const float* W2   = (const float*)d_in[7];
  const float* b2   = (const float*)d_in[8];

  char* ws = (char*)d_ws;
  u32* hPk      = (u32*)(ws + O_HPK);
  u32* fl       = (u32*)(ws + O_FL);
  u16* whhHi    = (u16*)(ws + O_WHH_HI);
  u16* whhLo    = (u16*)(ws + O_WHH_LO);
  u16* wihHi    = (u16*)(ws + O_WIH_HI);
  u16* wihLo    = (u16*)(ws + O_WIH_LO);
  float* bias   = (float*)(ws + O_BIAS);
  float* hT     = (float*)(ws + O_HT);
  float* zbuf   = (float*)(ws + O_Z);

  (void)hipMemsetAsync(ws, 0, O_MSET, stream);

  prep_weights<<<G_, 128, 0, stream>>>(Wih, Whh, bih, bhh, whhHi, whhLo, wihHi, wihLo, bias);

  (void)hipFuncSetAttribute((const void*)lstm_persistent,
                            hipFuncAttributeMaxDynamicSharedMemorySize, SMEM_BYTES);

  lstm_persistent<<<256, 576, SMEM_BYTES, stream>>>(x, whhHi, whhLo, wihHi, wihLo,
                                                    bias, hPk, fl, hT);

  head1<<<dim3(LH_ / 64, B_ / 64), 256, 0, stream>>>(hT, W1, b1, zbuf);
  head2<<<B_, 256, 0, stream>>>(zbuf, W2, b2, (float*)d_out);
}

// Round 9
// 9124.229 us; speedup vs baseline: 1.7502x; 1.7502x over previous
//
#include <hip/hip_runtime.h>

typedef unsigned short u16;
typedef unsigned int u32;
typedef __attribute__((ext_vector_type(8))) short bf16x8;
typedef __attribute__((ext_vector_type(4))) float f32x4;
typedef __attribute__((ext_vector_type(4))) unsigned int u32x4;

#define B_ 512
#define T_ 1024
#define F_ 128
#define H_ 512
#define G_ 2048
#define LH_ 1024

#define MFMA16(a,b,c) (c) = __builtin_amdgcn_mfma_f32_16x16x32_bf16((a),(b),(c),0,0,0)

__device__ __forceinline__ u16 f2bf(float f) {
  unsigned u = __float_as_uint(f);
  unsigned r = (u + 0x7fffu + ((u >> 16) & 1u)) >> 16;
  return (u16)r;
}
__device__ __forceinline__ float bf2f(u16 h) {
  return __uint_as_float(((unsigned)h) << 16);
}

// ---------------- workspace layout (bytes) ----------------
constexpr size_t O_HPK     = 0;                               // u32 packed h, 2 bufs: 2 MB
constexpr size_t O_FL      = O_HPK + (size_t)2 * B_ * H_ * 4; // per-producer step flags
constexpr size_t O_MSET    = O_FL + 4096;                     // memset [0, O_MSET)
constexpr size_t O_WHH_HI  = O_MSET;
constexpr size_t O_WHH_LO  = O_WHH_HI + (size_t)G_ * H_ * 2;
constexpr size_t O_WIH_HI  = O_WHH_LO + (size_t)G_ * H_ * 2;
constexpr size_t O_WIH_LO  = O_WIH_HI + (size_t)G_ * F_ * 2;
constexpr size_t O_BIAS    = O_WIH_LO + (size_t)G_ * F_ * 2;
constexpr size_t O_HT      = O_BIAS + (size_t)G_ * 4;
constexpr size_t O_Z       = O_HT + (size_t)B_ * H_ * 4;

// ---------------- LDS layout ----------------
constexpr unsigned SM_WHH_LO = 65536;    // sWhhHi [64][512] u16 swizzled at 0
constexpr unsigned SM_XC     = 131072;   // partial-acc exchange [4 rt][16 j][64 l] f32 = 16 KB
constexpr unsigned SM_BIAS   = 147456;   // f32[64]
constexpr unsigned SMEM_BYTES = 147712;

// ---------------- weight prep: permute + split to hi/lo bf16 ----------------
// permuted gate-col P = 64*nb + 16*g + u'  (unit u = 16*nb + u', g in {i,f,g,o})
__global__ void prep_weights(const float* __restrict__ Wih, const float* __restrict__ Whh,
                             const float* __restrict__ bih, const float* __restrict__ bhh,
                             u16* __restrict__ WhhHi, u16* __restrict__ WhhLo,
                             u16* __restrict__ WihHi, u16* __restrict__ WihLo,
                             float* __restrict__ bias) {
  int P = blockIdx.x;
  int nb = P >> 6, g = (P >> 4) & 3, u = P & 15;
  int orig = g * H_ + (nb << 4) + u;
  for (int k = threadIdx.x; k < H_; k += 128) {
    float w = Whh[(size_t)orig * H_ + k];
    u16 hi = f2bf(w);
    WhhHi[(size_t)P * H_ + k] = hi;
    WhhLo[(size_t)P * H_ + k] = f2bf(w - bf2f(hi));
  }
  {
    int k = threadIdx.x;
    float w = Wih[(size_t)orig * F_ + k];
    u16 hi = f2bf(w);
    WihHi[(size_t)P * F_ + k] = hi;
    WihLo[(size_t)P * F_ + k] = f2bf(w - bf2f(hi));
  }
  if (threadIdx.x == 0) bias[P] = bih[orig] + bhh[orig];
}

// ---------------- helpers ----------------
__device__ __forceinline__ u32x4 ald16(const u32* p) {   // system-coherent 16B load
  u32x4 r;
  asm volatile("global_load_dwordx4 %0, %1, off sc0 sc1" : "=&v"(r) : "v"(p));
  return r;
}
__device__ __forceinline__ u32x4 pld16(const float* p) { // plain cacheable 16B load
  u32x4 r;
  asm volatile("global_load_dwordx4 %0, %1, off" : "=&v"(r) : "v"(p));
  return r;
}

__device__ __forceinline__ void unpack(u32x4 a, u32x4 b, bf16x8& hi, bf16x8& lo) {
  #pragma unroll
  for (int j = 0; j < 4; ++j) { hi[j] = (short)(a[j] & 0xffffu); lo[j] = (short)(a[j] >> 16); }
  #pragma unroll
  for (int j = 0; j < 4; ++j) { hi[4 + j] = (short)(b[j] & 0xffffu); lo[4 + j] = (short)(b[j] >> 16); }
}

__device__ __forceinline__ void cvt8(u32x4 a, u32x4 b, bf16x8& hi, bf16x8& lo) {
  #pragma unroll
  for (int j = 0; j < 8; ++j) {
    float f = __uint_as_float(j < 4 ? a[j] : b[j - 4]);
    u16 h = f2bf(f);
    hi[j] = (short)h;
    lo[j] = (short)f2bf(f - bf2f(h));
  }
}

// full-row XOR swizzle: rows r and r+8 land in different 16B slots (conflict fix)
__device__ __forceinline__ bf16x8 ldB(const u16* base, int r, int k8) {
  return *(const bf16x8*)(base + r * 512 + ((k8 ^ (r & 63)) << 3));
}

// ---------------- persistent LSTM kernel ----------------
// grid 256 = 8 row-groups (m = bid&7) x 32 unit-blocks (nb = bid>>3)
// 512 threads = 8 waves = 4 row-tiles (rt) x 2 K-halves (cp)
__global__ __launch_bounds__(512, 2) void lstm_persistent(
    const float* __restrict__ x,
    const u16* __restrict__ WhhHi, const u16* __restrict__ WhhLo,
    const u16* __restrict__ WihHi, const u16* __restrict__ WihLo,
    const float* __restrict__ bias,
    u32* __restrict__ hPk, u32* __restrict__ fl, float* __restrict__ hT) {
  extern __shared__ char smem[];
  u16* sWhhHi  = (u16*)(smem);
  u16* sWhhLo  = (u16*)(smem + SM_WHH_LO);
  float* sXc   = (float*)(smem + SM_XC);
  float* sBias = (float*)(smem + SM_BIAS);

  const int tid = threadIdx.x;
  const int w = tid >> 6, l = tid & 63;
  const int m  = blockIdx.x & 7;
  const int nb = blockIdx.x >> 3;
  const int Pbase = 64 * nb;
  const int l15 = l & 15, l4 = l >> 4;
  const int rt = w >> 1, cp = w & 1;

  // ---- one-time: resident Whh slice (swizzled r&63), bias ----
  for (int i = tid; i < 4096; i += 512) {
    int r = i >> 6, k8 = i & 63;
    unsigned dst = r * 512 + ((k8 ^ (r & 63)) << 3);
    *(bf16x8*)(sWhhHi + dst) = *(const bf16x8*)(WhhHi + (size_t)(Pbase + r) * H_ + k8 * 8);
    *(bf16x8*)(sWhhLo + dst) = *(const bf16x8*)(WhhLo + (size_t)(Pbase + r) * H_ + k8 * 8);
  }
  if (tid < 64) sBias[tid] = bias[Pbase + tid];

  // ---- one-time: Wih fragments into registers (4 col-tiles x 2 k-chunks of this K-half) ----
  bf16x8 wfh[4][2], wfl[4][2];
  #pragma unroll
  for (int ct = 0; ct < 4; ++ct)
    #pragma unroll
    for (int ch = 0; ch < 2; ++ch) {
      int gcol = 16 * ct + l15;
      int k8i = 8 * cp + 4 * ch + l4;
      wfh[ct][ch] = *(const bf16x8*)(WihHi + (size_t)(Pbase + gcol) * F_ + k8i * 8);
      wfl[ct][ch] = *(const bf16x8*)(WihLo + (size_t)(Pbase + gcol) * F_ + k8i * 8);
    }
  __syncthreads();

  const float bi = sBias[l15], bf_ = sBias[16 + l15], bg = sBias[32 + l15], bo = sBias[48 + l15];
  const int arow = 64 * m + 16 * rt + l15;

  // prologue: x(0) prefetch (this wave's K-half of F), drained before loop
  u32x4 xa[2], xb[2];
  {
    const float* xr = x + (size_t)arow * T_ * F_ + 64 * cp + 8 * l4;
    xa[0] = pld16(xr);      xb[0] = pld16(xr + 4);
    xa[1] = pld16(xr + 32); xb[1] = pld16(xr + 36);
  }
  asm volatile("s_waitcnt vmcnt(0)" ::: "memory");

  float cr[4] = {0.f, 0.f, 0.f, 0.f};   // cell state, cp0 only, static q-index

  #pragma unroll 1
  for (int t = 0; t < T_; ++t) {
    const u32* hcur = hPk + (size_t)(t & 1) * B_ * H_;
    u32* hnxt = hPk + (size_t)((t & 1) ^ 1) * B_ * H_;

    f32x4 acc0 = {0.f,0.f,0.f,0.f}, acc1 = {0.f,0.f,0.f,0.f};
    f32x4 acc2 = {0.f,0.f,0.f,0.f}, acc3 = {0.f,0.f,0.f,0.f};

    // ---- per-wave poll: only this K-half's 16 producers (lanes 0..15) ----
    if (t > 0 && l < 16) {
      const u32* fp = fl + m * 32 + 16 * cp + l;
      long fuse = 400000000;
      while (__hip_atomic_load(fp, __ATOMIC_RELAXED, __HIP_MEMORY_SCOPE_SYSTEM) < (u32)t) {
        __builtin_amdgcn_s_sleep(1);
        if (--fuse == 0) break;
      }
    }

    // ---- issue ALL 8 h chunks (16 loads) upfront ----
    u32x4 Aa[8], Ab[8];
    const u32* hrowt = hcur + (size_t)arow * H_ + 256 * cp + 8 * l4;
    if (t > 0) {
      #pragma unroll
      for (int c = 0; c < 8; ++c) {
        Aa[c] = ald16(hrowt + c * 32);
        Ab[c] = ald16(hrowt + c * 32 + 4);
      }
    }

    // ---- x-part (this K-half of F), overlaps h-load flight ----
    #pragma unroll
    for (int ch = 0; ch < 2; ++ch) {
      bf16x8 xh, xl;
      cvt8(xa[ch], xb[ch], xh, xl);
      MFMA16(xh, wfh[0][ch], acc0); MFMA16(xl, wfh[0][ch], acc0); MFMA16(xh, wfl[0][ch], acc0);
      MFMA16(xh, wfh[1][ch], acc1); MFMA16(xl, wfh[1][ch], acc1); MFMA16(xh, wfl[1][ch], acc1);
      MFMA16(xh, wfh[2][ch], acc2); MFMA16(xl, wfh[2][ch], acc2); MFMA16(xh, wfl[2][ch], acc2);
      MFMA16(xh, wfh[3][ch], acc3); MFMA16(xl, wfh[3][ch], acc3); MFMA16(xh, wfl[3][ch], acc3);
    }

    // ---- h-part: 8 K=32 chunks over this K-half, all 64 cols, counted drain ----
    if (t > 0) {
      #pragma unroll
      for (int ch = 0; ch < 8; ++ch) {
        if (ch == 0)      asm volatile("s_waitcnt vmcnt(14)");
        else if (ch == 1) asm volatile("s_waitcnt vmcnt(12)");
        else if (ch == 2) asm volatile("s_waitcnt vmcnt(10)");
        else if (ch == 3) asm volatile("s_waitcnt vmcnt(8)");
        else if (ch == 4) asm volatile("s_waitcnt vmcnt(6)");
        else if (ch == 5) asm volatile("s_waitcnt vmcnt(4)");
        else if (ch == 6) asm volatile("s_waitcnt vmcnt(2)");
        else              asm volatile("s_waitcnt vmcnt(0)");
        __builtin_amdgcn_sched_barrier(0);
        bf16x8 ah, al;
        unpack(Aa[ch], Ab[ch], ah, al);
        int k8 = 32 * cp + 4 * ch + l4;
        bf16x8 bh, bl;
        bh = ldB(sWhhHi, l15, k8);      bl = ldB(sWhhLo, l15, k8);
        MFMA16(ah, bh, acc0); MFMA16(al, bh, acc0); MFMA16(ah, bl, acc0);
        bh = ldB(sWhhHi, 16 + l15, k8); bl = ldB(sWhhLo, 16 + l15, k8);
        MFMA16(ah, bh, acc1); MFMA16(al, bh, acc1); MFMA16(ah, bl, acc1);
        bh = ldB(sWhhHi, 32 + l15, k8); bl = ldB(sWhhLo, 32 + l15, k8);
        MFMA16(ah, bh, acc2); MFMA16(al, bh, acc2); MFMA16(ah, bl, acc2);
        bh = ldB(sWhhHi, 48 + l15, k8); bl = ldB(sWhhLo, 48 + l15, k8);
        MFMA16(ah, bh, acc3); MFMA16(al, bh, acc3); MFMA16(ah, bl, acc3);
      }
    }

    // ---- cp1: publish K-high partials (conflict-free transposed layout) ----
    if (cp == 1) {
      float* bse = sXc + (rt * 16) * 64 + l;
      bse[0 * 64]  = acc0[0]; bse[1 * 64]  = acc0[1]; bse[2 * 64]  = acc0[2]; bse[3 * 64]  = acc0[3];
      bse[4 * 64]  = acc1[0]; bse[5 * 64]  = acc1[1]; bse[6 * 64]  = acc1[2]; bse[7 * 64]  = acc1[3];
      bse[8 * 64]  = acc2[0]; bse[9 * 64]  = acc2[1]; bse[10 * 64] = acc2[2]; bse[11 * 64] = acc2[3];
      bse[12 * 64] = acc3[0]; bse[13 * 64] = acc3[1]; bse[14 * 64] = acc3[2]; bse[15 * 64] = acc3[3];
    }

    __syncthreads();   // A: partials published

    // ---- x(t+1) prefetch (drains at step-end vmcnt(0)) ----
    {
      int tp = (t + 1 < T_) ? t + 1 : 0;
      const float* xr = x + (size_t)arow * T_ * F_ + (size_t)tp * F_ + 64 * cp + 8 * l4;
      xa[0] = pld16(xr);      xb[0] = pld16(xr + 4);
      xa[1] = pld16(xr + 32); xb[1] = pld16(xr + 36);
    }

    // ---- cp0: fold partials, elementwise update (c in VGPRs), packed system h store ----
    if (cp == 0) {
      const float* bse = sXc + (rt * 16) * 64 + l;
      float p[16];
      #pragma unroll
      for (int j = 0; j < 16; ++j) p[j] = bse[j * 64];
      #pragma unroll
      for (int q = 0; q < 4; ++q) {
        float gi = acc0[q] + p[q]      + bi;
        float gf = acc1[q] + p[4 + q]  + bf_;
        float gg = acc2[q] + p[8 + q]  + bg;
        float go = acc3[q] + p[12 + q] + bo;
        float ii = 1.f / (1.f + __expf(-gi));
        float ff = 1.f / (1.f + __expf(-gf));
        float gG = 1.f - 2.f / (__expf(2.f * gg) + 1.f);
        float oo = 1.f / (1.f + __expf(-go));
        float c = ff * cr[q] + ii * gG;
        cr[q] = c;
        float h = oo * (1.f - 2.f / (__expf(2.f * c) + 1.f));
        u16 hb = f2bf(h);
        u16 lb = f2bf(h - bf2f(hb));
        u32 pk = (u32)hb | ((u32)lb << 16);
        size_t idx = (size_t)(64 * m + 16 * rt + 4 * l4 + q) * H_ + 16 * nb + l15;
        __hip_atomic_store(&hnxt[idx], pk, __ATOMIC_RELAXED, __HIP_MEMORY_SCOPE_SYSTEM);
        if (t == T_ - 1) hT[idx] = h;
      }
    }

    // ---- drain (per wave), barrier, single flag store, isolate from vmcnt ----
    asm volatile("s_waitcnt vmcnt(0)" ::: "memory");
    __syncthreads();   // B
    if (tid == 0) {
      __hip_atomic_store(&fl[m * 32 + nb], (u32)(t + 1), __ATOMIC_RELAXED, __HIP_MEMORY_SCOPE_SYSTEM);
      asm volatile("s_waitcnt vmcnt(0)" ::: "memory");
    }
  }
}

// ---------------- head: z = relu(hT @ W1^T + b1) ----------------
__global__ __launch_bounds__(256) void head1(const float* __restrict__ hT,
                                             const float* __restrict__ W1,
                                             const float* __restrict__ b1,
                                             float* __restrict__ z) {
  __shared__ float sA[64][16];
  __shared__ float sBt[16][64];
  int tx = threadIdx.x & 15, ty = threadIdx.x >> 4;
  int row0 = blockIdx.y * 64, col0 = blockIdx.x * 64;
  float acc[4][4] = {};
  for (int k0 = 0; k0 < H_; k0 += 16) {
    int c = threadIdx.x >> 2, kk4 = (threadIdx.x & 3) * 4;
    float4 av = *(const float4*)(hT + (size_t)(row0 + c) * H_ + k0 + kk4);
    *(float4*)&sA[c][kk4] = av;
    float4 bv = *(const float4*)(W1 + (size_t)(col0 + c) * H_ + k0 + kk4);
    sBt[kk4 + 0][c] = bv.x; sBt[kk4 + 1][c] = bv.y;
    sBt[kk4 + 2][c] = bv.z; sBt[kk4 + 3][c] = bv.w;
    __syncthreads();
    #pragma unroll
    for (int kk = 0; kk < 16; ++kk) {
      float a0 = sA[ty * 4 + 0][kk], a1 = sA[ty * 4 + 1][kk];
      float a2 = sA[ty * 4 + 2][kk], a3 = sA[ty * 4 + 3][kk];
      float b0 = sBt[kk][tx * 4 + 0], b1v = sBt[kk][tx * 4 + 1];
      float b2v = sBt[kk][tx * 4 + 2], b3 = sBt[kk][tx * 4 + 3];
      acc[0][0] += a0 * b0; acc[0][1] += a0 * b1v; acc[0][2] += a0 * b2v; acc[0][3] += a0 * b3;
      acc[1][0] += a1 * b0; acc[1][1] += a1 * b1v; acc[1][2] += a1 * b2v; acc[1][3] += a1 * b3;
      acc[2][0] += a2 * b0; acc[2][1] += a2 * b1v; acc[2][2] += a2 * b2v; acc[2][3] += a2 * b3;
      acc[3][0] += a3 * b0; acc[3][1] += a3 * b1v; acc[3][2] += a3 * b2v; acc[3][3] += a3 * b3;
    }
    __syncthreads();
  }
  #pragma unroll
  for (int i = 0; i < 4; ++i)
    #pragma unroll
    for (int j = 0; j < 4; ++j) {
      int rr = row0 + ty * 4 + i, cc = col0 + tx * 4 + j;
      float v = acc[i][j] + b1[cc];
      z[(size_t)rr * LH_ + cc] = v > 0.f ? v : 0.f;
    }
}

// ---------------- head: out[b] = z[b,:] . W2 + b2 ----------------
__global__ __launch_bounds__(256) void head2(const float* __restrict__ z,
                                             const float* __restrict__ W2,
                                             const float* __restrict__ b2,
                                             float* __restrict__ out) {
  int b = blockIdx.x;
  float p = 0.f;
  for (int j = threadIdx.x; j < LH_; j += 256) p += z[(size_t)b * LH_ + j] * W2[j];
  #pragma unroll
  for (int off = 32; off > 0; off >>= 1) p += __shfl_down(p, off);
  __shared__ float red[4];
  if ((threadIdx.x & 63) == 0) red[threadIdx.x >> 6] = p;
  __syncthreads();
  if (threadIdx.x == 0) out[b] = red[0] + red[1] + red[2] + red[3] + b2[0];
}

// ---------------- launch ----------------
extern "C" void kernel_launch(void* const* d_in, const int* in_sizes, int n_in,
                              void* d_out, int out_size, void* d_ws, size_t ws_size,
                              hipStream_t stream) {
  const float* x    = (const float*)d_in[0];
  const float* Wih  = (const float*)d_in[1];
  const float* Whh  = (const float*)d_in[2];
  const float* bih  = (const float*)d_in[3];
  const float* bhh  = (const float*)d_in[4];
  const float* W1   = (const float*)d_in[5];
  const float* b1   = (const float*)d_in[6];
  const float* W2   = (const float*)d_in[7];
  const float* b2   = (const float*)d_in[8];

  char* ws = (char*)d_ws;
  u32* hPk      = (u32*)(ws + O_HPK);
  u32* fl       = (u32*)(ws + O_FL);
  u16* whhHi    = (u16*)(ws + O_WHH_HI);
  u16* whhLo    = (u16*)(ws + O_WHH_LO);
  u16* wihHi    = (u16*)(ws + O_WIH_HI);
  u16* wihLo    = (u16*)(ws + O_WIH_LO);
  float* bias   = (float*)(ws + O_BIAS);
  float* hT     = (float*)(ws + O_HT);
  float* zbuf   = (float*)(ws + O_Z);

  (void)hipMemsetAsync(ws, 0, O_MSET, stream);

  prep_weights<<<G_, 128, 0, stream>>>(Wih, Whh, bih, bhh, whhHi, whhLo, wihHi, wihLo, bias);

  (void)hipFuncSetAttribute((const void*)lstm_persistent,
                            hipFuncAttributeMaxDynamicSharedMemorySize, SMEM_BYTES);

  lstm_persistent<<<256, 512, SMEM_BYTES, stream>>>(x, whhHi, whhLo, wihHi, wihLo,
                                                    bias, hPk, fl, hT);

  head1<<<dim3(LH_ / 64, B_ / 64), 256, 0, stream>>>(hT, W1, b1, zbuf);
  head2<<<B_, 256, 0, stream>>>(zbuf, W2, b2, (float*)d_out);
}